// Round 3
// baseline (197.602 us; speedup 1.0000x reference)
//
#include <hip/hip_runtime.h>

// loss = (1/N) * sum_i || features[i] - center[labels[i]] ||_2
// N=32768, C=1000, D=512, fp32. Memory-bound: stream 64 MiB of features once.

__global__ __launch_bounds__(256) void intra_loss_kernel(
    const float* __restrict__ features,
    const int*   __restrict__ labels,
    const float* __restrict__ center,
    float*       __restrict__ out,
    int N)
{
    const int lane  = threadIdx.x & 63;
    const int wid   = threadIdx.x >> 6;                    // wave within block
    const int wpb   = blockDim.x >> 6;                     // waves per block
    const int gwave = blockIdx.x * wpb + wid;
    const int nwv   = gridDim.x * wpb;

    float acc = 0.0f;  // lane-0 running sum of distances for this wave's rows

    for (int row = gwave; row < N; row += nwv) {
        const float4* f = reinterpret_cast<const float4*>(features + (size_t)row * 512);
        const int lbl   = labels[row];                     // wave-uniform -> broadcast
        const float4* c = reinterpret_cast<const float4*>(center + (size_t)lbl * 512);

        float ss = 0.0f;
        #pragma unroll
        for (int p = 0; p < 2; ++p) {                      // 2 passes x 64 lanes x float4 = 512 floats
            const float4 fv = f[p * 64 + lane];
            const float4 cv = c[p * 64 + lane];
            const float dx = fv.x - cv.x;
            const float dy = fv.y - cv.y;
            const float dz = fv.z - cv.z;
            const float dw = fv.w - cv.w;
            ss += dx * dx + dy * dy + dz * dz + dw * dw;
        }

        // 64-lane reduce (shfl_down tree, width 64)
        #pragma unroll
        for (int off = 32; off > 0; off >>= 1)
            ss += __shfl_down(ss, off, 64);

        if (lane == 0)
            acc += sqrtf(ss);
    }

    if (lane == 0)
        atomicAdd(out, acc * (1.0f / 32768.0f));           // device-scope by default
}

extern "C" void kernel_launch(void* const* d_in, const int* in_sizes, int n_in,
                              void* d_out, int out_size, void* d_ws, size_t ws_size,
                              hipStream_t stream) {
    const float* features = (const float*)d_in[0];
    const int*   labels   = (const int*)d_in[1];
    const float* center   = (const float*)d_in[2];
    float* out = (float*)d_out;

    const int N = 32768;

    // d_out is re-poisoned to 0xAA before every timed replay -> must zero it here.
    hipMemsetAsync(out, 0, sizeof(float), stream);

    const int block = 256;
    const int grid  = 2048;  // 8192 waves, 4 rows each (memory-bound sizing, G11)
    intra_loss_kernel<<<grid, block, 0, stream>>>(features, labels, center, out, N);
}

// Round 4
// 97.654 us; speedup vs baseline: 2.0235x; 2.0235x over previous
//
#include <hip/hip_runtime.h>

// loss = (1/N) * sum_i || features[i] - center[labels[i]] ||_2
// N=32768, C=1000, D=512, fp32.
// R3 lesson: 8192 same-address atomicAdds serialized the kernel (117us,
// WRITE_SIZE=256KB = atomic cacheline bounce). Now: block-reduce -> d_ws
// partials -> tiny second kernel. Zero global atomics.

#define GRID  1024
#define BLOCK 256
// 4096 waves total, 32768/4096 = 8 rows per wave (compile-time constant).

__global__ __launch_bounds__(BLOCK) void intra_partial(
    const float* __restrict__ features,
    const int*   __restrict__ labels,
    const float* __restrict__ center,
    float*       __restrict__ partial)
{
    const int lane  = threadIdx.x & 63;
    const int wid   = threadIdx.x >> 6;               // wave in block (0..3)
    const int gwave = blockIdx.x * 4 + wid;           // 0..4095

    float acc = 0.0f;                                  // lane-0 sum of sqrt distances

    #pragma unroll
    for (int k = 0; k < 8; ++k) {
        const int row = gwave + k * 4096;              // coalesced across waves
        const int lbl = labels[row];                   // wave-uniform
        const float4* f = reinterpret_cast<const float4*>(features + (size_t)row * 512);
        const float4* c = reinterpret_cast<const float4*>(center   + (size_t)lbl * 512);

        float ss = 0.0f;
        #pragma unroll
        for (int p = 0; p < 2; ++p) {                  // 2 x 64 lanes x float4 = 512 floats
            const float4 fv = f[p * 64 + lane];
            const float4 cv = c[p * 64 + lane];
            const float dx = fv.x - cv.x;
            const float dy = fv.y - cv.y;
            const float dz = fv.z - cv.z;
            const float dw = fv.w - cv.w;
            ss += dx * dx + dy * dy + dz * dz + dw * dw;
        }

        #pragma unroll
        for (int off = 32; off > 0; off >>= 1)
            ss += __shfl_down(ss, off, 64);

        if (lane == 0)
            acc += sqrtf(ss);
    }

    __shared__ float s[4];
    if (lane == 0) s[wid] = acc;
    __syncthreads();
    if (threadIdx.x == 0)
        partial[blockIdx.x] = s[0] + s[1] + s[2] + s[3];
}

__global__ __launch_bounds__(1024) void final_reduce(
    const float* __restrict__ partial,
    float*       __restrict__ out)
{
    float v = partial[threadIdx.x];                    // exactly GRID=1024 partials

    #pragma unroll
    for (int off = 32; off > 0; off >>= 1)
        v += __shfl_down(v, off, 64);

    __shared__ float s[16];
    if ((threadIdx.x & 63) == 0) s[threadIdx.x >> 6] = v;
    __syncthreads();
    if (threadIdx.x == 0) {
        float t = 0.0f;
        #pragma unroll
        for (int i = 0; i < 16; ++i) t += s[i];
        *out = t * (1.0f / 32768.0f);                  // unconditional write: no memset needed
    }
}

extern "C" void kernel_launch(void* const* d_in, const int* in_sizes, int n_in,
                              void* d_out, int out_size, void* d_ws, size_t ws_size,
                              hipStream_t stream) {
    const float* features = (const float*)d_in[0];
    const int*   labels   = (const int*)d_in[1];
    const float* center   = (const float*)d_in[2];
    float* out     = (float*)d_out;
    float* partial = (float*)d_ws;                     // 1024 floats of scratch

    intra_partial<<<GRID, BLOCK, 0, stream>>>(features, labels, center, partial);
    final_reduce<<<1, 1024, 0, stream>>>(partial, out);
}